// Round 7
// baseline (703.745 us; speedup 1.0000x reference)
//
#include <hip/hip_runtime.h>
#include <math.h>

#define EM_EPS 1e-8f
#define BN_SC 0.999995000037f   // 1/sqrt(1+1e-5)
#define LOG2PI 1.8378770664093453f

// ---------------- conv1 (5x5 s2 VALID) + bn1 ----------------
// x (32,3,32,32), w (256,3,5,5) -> out (32,256,14,14)
__global__ __launch_bounds__(256) void k_conv1(
    const float* __restrict__ x, const float* __restrict__ w,
    const float* __restrict__ g, const float* __restrict__ bb,
    float* __restrict__ out) {
  int idx = blockIdx.x * 256 + threadIdx.x;
  int ox = idx % 14; int t = idx / 14;
  int oy = t % 14; t /= 14;
  int co = t % 256; int b = t / 256;
  const float* xb = x + b * 3 * 1024;
  const float* wc = w + co * 75;
  float acc = 0.f;
  #pragma unroll
  for (int ci = 0; ci < 3; ++ci) {
    const float* xc = xb + ci * 1024 + (oy * 2) * 32 + ox * 2;
    const float* wk = wc + ci * 25;
    #pragma unroll
    for (int kh = 0; kh < 5; ++kh)
      #pragma unroll
      for (int kw = 0; kw < 5; ++kw)
        acc = fmaf(xc[kh * 32 + kw], wk[kh * 5 + kw], acc);
  }
  out[idx] = acc * (g[co] * BN_SC) + bb[co];
}

// ------------- conv2 partial (K-split over 4 blocks) -------------
__global__ __launch_bounds__(192) void k_conv2_part(
    const float* __restrict__ in,
    const float* __restrict__ wa, const float* __restrict__ wp,
    float* __restrict__ partial) {
  __shared__ float s_in[16 * 14 * 16];   // [ci][iy][ix pad16]
  __shared__ float s_w[16 * 9 * 34];     // [ci][tap][co pad34]

  const int t   = threadIdx.x;
  const int row = t >> 4;
  const int cg  = t & 15;
  const int b   = blockIdx.x / 36;
  const int r36 = blockIdx.x % 36;
  const int gco = (r36 >> 2) * 32;
  const int kc  = r36 & 3;
  const float* inb = in + b * 50176;

  float acc[2][12];
  #pragma unroll
  for (int u = 0; u < 2; ++u)
    #pragma unroll
    for (int px = 0; px < 12; ++px) acc[u][px] = 0.f;

  for (int ch = kc * 4; ch < kc * 4 + 4; ++ch) {
    __syncthreads();
    for (int idx = t; idx < 3136; idx += 192) {
      int ci = idx / 196, r = idx - ci * 196;
      int iy = r / 14, ix = r - iy * 14;
      s_in[ci * 224 + iy * 16 + ix] = inb[ch * 3136 + idx];
    }
    for (int idx = t; idx < 4608; idx += 192) {
      int co = idx / 144, rem = idx - co * 144;
      int c = gco + co;
      float val = 0.f;
      if (c < 272) {
        const float* wrow = (c < 16) ? (wa + c * 2304) : (wp + (c - 16) * 2304);
        val = wrow[ch * 144 + rem];
      }
      s_w[rem * 34 + co] = val;
    }
    __syncthreads();

    for (int ci = 0; ci < 16; ++ci) {
      float rin[3][16];
      #pragma unroll
      for (int kh = 0; kh < 3; ++kh) {
        const float4* rp = (const float4*)&s_in[ci * 224 + (row + kh) * 16];
        #pragma unroll
        for (int x = 0; x < 4; ++x)
          *(float4*)&rin[kh][x * 4] = rp[x];
      }
      #pragma unroll
      for (int kh = 0; kh < 3; ++kh) {
        #pragma unroll
        for (int kw = 0; kw < 3; ++kw) {
          float2 wv = *(const float2*)&s_w[(ci * 9 + kh * 3 + kw) * 34 + cg * 2];
          #pragma unroll
          for (int px = 0; px < 12; ++px) {
            float iv = rin[kh][px + kw];
            acc[0][px] = fmaf(iv, wv.x, acc[0][px]);
            acc[1][px] = fmaf(iv, wv.y, acc[1][px]);
          }
        }
      }
    }
  }

  #pragma unroll
  for (int u = 0; u < 2; ++u) {
    int c = gco + cg * 2 + u;
    float* dst = partial + ((size_t)(kc * 32 + b) * 288 + c) * 144 + row * 12;
    #pragma unroll
    for (int px = 0; px < 12; ++px) dst[px] = acc[u][px];
  }
}

// ------------- conv2 reduce: sum 4 partials + bn (+sigmoid for a) -------------
__global__ __launch_bounds__(256) void k_conv2_red(
    const float* __restrict__ partial,
    const float* __restrict__ ga, const float* __restrict__ bba,
    const float* __restrict__ gp, const float* __restrict__ bbp,
    float* __restrict__ a1, float* __restrict__ pose1) {
  int idx = blockIdx.x * 256 + threadIdx.x;
  if (idx >= 32 * 272 * 144) return;
  int px = idx % 144; int r = idx / 144;
  int c = r % 272; int b = r / 272;
  const size_t base = ((size_t)b * 288 + c) * 144 + px;
  const size_t kstr = (size_t)32 * 288 * 144;
  float s = partial[base] + partial[base + kstr]
          + partial[base + 2 * kstr] + partial[base + 3 * kstr];
  if (c < 16) {
    float v = s * (ga[c] * BN_SC) + bba[c];
    a1[((size_t)b * 16 + c) * 144 + px] = 1.f / (1.f + expf(-v));
  } else {
    int cp = c - 16;
    pose1[((size_t)b * 256 + cp) * 144 + px] = s * (gp[cp] * BN_SC) + bbp[cp];
  }
}

// ------------- conv2 single-pass fallback (ws too small) -------------
__global__ __launch_bounds__(192) void k_conv2(
    const float* __restrict__ in,
    const float* __restrict__ wa, const float* __restrict__ wp,
    const float* __restrict__ ga, const float* __restrict__ bba,
    const float* __restrict__ gp, const float* __restrict__ bbp,
    float* __restrict__ a1, float* __restrict__ pose1) {
  __shared__ float s_in[16 * 14 * 16];
  __shared__ float s_w[16 * 9 * 34];

  const int t   = threadIdx.x;
  const int row = t >> 4;
  const int cg  = t & 15;
  const int b   = blockIdx.x / 9;
  const int gco = (blockIdx.x % 9) * 32;
  const float* inb = in + b * 50176;

  float acc[2][12];
  #pragma unroll
  for (int u = 0; u < 2; ++u)
    #pragma unroll
    for (int px = 0; px < 12; ++px) acc[u][px] = 0.f;

  for (int ch = 0; ch < 16; ++ch) {
    __syncthreads();
    for (int idx = t; idx < 3136; idx += 192) {
      int ci = idx / 196, r = idx - ci * 196;
      int iy = r / 14, ix = r - iy * 14;
      s_in[ci * 224 + iy * 16 + ix] = inb[ch * 3136 + idx];
    }
    for (int idx = t; idx < 4608; idx += 192) {
      int co = idx / 144, rem = idx - co * 144;
      int c = gco + co;
      float val = 0.f;
      if (c < 272) {
        const float* wrow = (c < 16) ? (wa + c * 2304) : (wp + (c - 16) * 2304);
        val = wrow[ch * 144 + rem];
      }
      s_w[rem * 34 + co] = val;
    }
    __syncthreads();

    for (int ci = 0; ci < 16; ++ci) {
      float rin[3][16];
      #pragma unroll
      for (int kh = 0; kh < 3; ++kh) {
        const float4* rp = (const float4*)&s_in[ci * 224 + (row + kh) * 16];
        #pragma unroll
        for (int x = 0; x < 4; ++x)
          *(float4*)&rin[kh][x * 4] = rp[x];
      }
      #pragma unroll
      for (int kh = 0; kh < 3; ++kh) {
        #pragma unroll
        for (int kw = 0; kw < 3; ++kw) {
          float2 wv = *(const float2*)&s_w[(ci * 9 + kh * 3 + kw) * 34 + cg * 2];
          #pragma unroll
          for (int px = 0; px < 12; ++px) {
            float iv = rin[kh][px + kw];
            acc[0][px] = fmaf(iv, wv.x, acc[0][px]);
            acc[1][px] = fmaf(iv, wv.y, acc[1][px]);
          }
        }
      }
    }
  }

  #pragma unroll
  for (int u = 0; u < 2; ++u) {
    int c = gco + cg * 2 + u;
    if (c >= 272) continue;
    if (c < 16) {
      float g_ = ga[c] * BN_SC, b_ = bba[c];
      float* dst = a1 + ((b * 16 + c) * 12 + row) * 12;
      #pragma unroll
      for (int px = 0; px < 12; ++px) {
        float v = acc[u][px] * g_ + b_;
        dst[px] = 1.f / (1.f + expf(-v));
      }
    } else {
      int cp = c - 16;
      float g_ = gp[cp] * BN_SC, b_ = bbp[cp];
      float* dst = pose1 + ((b * 256 + cp) * 12 + row) * 12;
      #pragma unroll
      for (int px = 0; px < 12; ++px)
        dst[px] = acc[u][px] * g_ + b_;
    }
  }
}

// ---------------- EM routing v3: lane = (kq, j), all 16 p in-lane ----------------
// 256 threads = 4 waves; wave wv owns k in [wv*KPW, (wv+1)*KPW); within a
// quad-step, lane kq (=ln>>4) handles k = wv*KPW + st*4 + kq for capsule j.
// p-reductions are in-lane (no shuffles); only the j-softmax shuffles (4 per
// quad = 1 per k). W rows double-buffered in registers across steps.
template<int K, int S, int P, int HIN, int WIN, int OH, int OW, int B>
__global__ __launch_bounds__(256, 3) void k_routing(
    const float* __restrict__ ag,      // (b,16,HIN,WIN)
    const float* __restrict__ poseg,   // (b,256,HIN,WIN)
    const float* __restrict__ Wg,      // (KKA,B,4,4)
    const float* __restrict__ bu, const float* __restrict__ ba,
    const float* __restrict__ bng, const float* __restrict__ bnb,
    float* __restrict__ aout_g,        // (b,B,OH,OW)
    float* __restrict__ pose_out_g) {  // (b,B*16,OH,OW) or null
  constexpr int A = 16;
  constexpr int KK = K * K;
  constexpr int KKA = KK * A;
  constexpr int NW = 4;
  constexpr int KPW = KKA / NW;       // 36 or 64
  constexpr int NSTEP = KPW / 4;      // 9 or 16
  static_assert(KPW % 4 == 0, "KPW%4");

  __shared__ __attribute__((aligned(16))) float s_pp[KKA * 16];
  __shared__ float s_ain[KKA];
  __shared__ __attribute__((aligned(16))) float s_part[NW][16][36]; // U1[16]|U2[16]|RS pad36

  const int t  = threadIdx.x;
  const int wv = t >> 6;
  const int ln = t & 63;
  const int j  = ln & 15;
  const int kq = ln >> 4;
  const int jc = (j < B) ? j : 0;
  const bool jvalid = (j < B);

  const int bi = blockIdx.x;
  const int b  = bi / (OH * OW);
  const int l  = bi % (OH * OW);
  const int oy = l / OW, ox = l % OW;

  // ---- stage pose patch (+bn) and a patch into LDS ----
  for (int idx = t; idx < KKA * 16; idx += 256) {
    int k = idx >> 4, pe = idx & 15;
    int acap = k & 15, kki = k >> 4;
    int kh = kki / K, kw = kki % K;
    int iy = oy * S - P + kh, ix = ox * S - P + kw;
    float val = 0.f;
    if (iy >= 0 && iy < HIN && ix >= 0 && ix < WIN) {
      int c = acap * 16 + pe;
      val = poseg[((b * 256 + c) * HIN + iy) * WIN + ix];
      if (bng) val = val * (bng[c] * BN_SC) + bnb[c];
    }
    s_pp[idx] = val;
  }
  for (int k = t; k < KKA; k += 256) {
    int acap = k & 15, kki = k >> 4;
    int kh = kki / K, kw = kki % K;
    int iy = oy * S - P + kh, ix = ox * S - P + kw;
    float val = 0.f;
    if (iy >= 0 && iy < HIN && ix >= 0 && ix < WIN)
      val = ag[((b * A + acap) * HIN + iy) * WIN + ix];
    s_ain[k] = val;
  }
  __syncthreads();

  const float bu_j = bu[jc];
  const float ba_j = ba[jc];
  const int kbase = wv * KPW + kq;

  float mu[16], i2s[16];
  #pragma unroll
  for (int p = 0; p < 16; ++p) { mu[p] = 0.f; i2s[p] = 0.f; }
  float Ej = 0.f;

  float p95 = 0.95f;
  for (int it = 0; it < 3; ++it) {
    const float lam = 0.01f * (1.0f - p95);
    p95 *= 0.95f;
    float U1[16], U2[16], RS = 0.f;
    #pragma unroll
    for (int p = 0; p < 16; ++p) { U1[p] = 0.f; U2[p] = 0.f; }

    // W double-buffer in registers
    const float4* wp0 = (const float4*)(Wg + ((size_t)kbase * B + jc) * 16);
    float4 cw0 = wp0[0], cw1 = wp0[1], cw2 = wp0[2], cw3 = wp0[3];

    for (int st = 0; st < NSTEP; ++st) {
      float4 nw0, nw1, nw2, nw3;
      if (st + 1 < NSTEP) {
        const float4* np =
            (const float4*)(Wg + ((size_t)(kbase + (st + 1) * 4) * B + jc) * 16);
        nw0 = np[0]; nw1 = np[1]; nw2 = np[2]; nw3 = np[3];
      }
      const int k = kbase + st * 4;
      const float4* pr = (const float4*)&s_pp[k * 16];
      const float ain = s_ain[k];
      float vv[16];
      #pragma unroll
      for (int x2 = 0; x2 < 4; ++x2) {
        const float4 p4 = pr[x2];
        vv[x2 * 4 + 0] = p4.x * cw0.x + p4.y * cw1.x + p4.z * cw2.x + p4.w * cw3.x;
        vv[x2 * 4 + 1] = p4.x * cw0.y + p4.y * cw1.y + p4.z * cw2.y + p4.w * cw3.y;
        vv[x2 * 4 + 2] = p4.x * cw0.z + p4.y * cw1.z + p4.z * cw2.z + p4.w * cw3.z;
        vv[x2 * 4 + 3] = p4.x * cw0.w + p4.y * cw1.w + p4.z * cw2.w + p4.w * cw3.w;
      }
      float ra;
      if (it == 0) {
        ra = ain * (1.0f / (float)B);
      } else {
        float sa = 0.f, sb = 0.f, sc = 0.f, sd = 0.f;
        #pragma unroll
        for (int g = 0; g < 4; ++g) {
          float d0 = vv[g * 4 + 0] - mu[g * 4 + 0];
          float d1 = vv[g * 4 + 1] - mu[g * 4 + 1];
          float d2 = vv[g * 4 + 2] - mu[g * 4 + 2];
          float d3 = vv[g * 4 + 3] - mu[g * 4 + 3];
          sa = fmaf(d0 * i2s[g * 4 + 0], d0, sa);
          sb = fmaf(d1 * i2s[g * 4 + 1], d1, sb);
          sc = fmaf(d2 * i2s[g * 4 + 2], d2, sc);
          sd = fmaf(d3 * i2s[g * 4 + 3], d3, sd);
        }
        const float ss = (sa + sb) + (sc + sd);
        float e = Ej * __expf(-ss);
        float sm = e + __shfl_xor(e, 1);
        sm += __shfl_xor(sm, 2);
        sm += __shfl_xor(sm, 4);
        sm += __shfl_xor(sm, 8);
        ra = e * __builtin_amdgcn_rcpf(sm + 1e-30f) * ain;
      }
      RS += ra;
      #pragma unroll
      for (int p = 0; p < 16; ++p) {
        float tv = ra * vv[p];
        U1[p] += tv;
        U2[p] = fmaf(tv, vv[p], U2[p]);
      }
      if (st + 1 < NSTEP) { cw0 = nw0; cw1 = nw1; cw2 = nw2; cw3 = nw3; }
    }

    // ---- reduce over kq (in-wave butterfly) ----
    #pragma unroll
    for (int p = 0; p < 16; ++p) {
      U1[p] += __shfl_xor(U1[p], 16); U1[p] += __shfl_xor(U1[p], 32);
      U2[p] += __shfl_xor(U2[p], 16); U2[p] += __shfl_xor(U2[p], 32);
    }
    RS += __shfl_xor(RS, 16); RS += __shfl_xor(RS, 32);

    // ---- cross-wave exchange ----
    if (ln < 16) {
      float4* dst = (float4*)&s_part[wv][ln][0];
      dst[0] = make_float4(U1[0], U1[1], U1[2], U1[3]);
      dst[1] = make_float4(U1[4], U1[5], U1[6], U1[7]);
      dst[2] = make_float4(U1[8], U1[9], U1[10], U1[11]);
      dst[3] = make_float4(U1[12], U1[13], U1[14], U1[15]);
      dst[4] = make_float4(U2[0], U2[1], U2[2], U2[3]);
      dst[5] = make_float4(U2[4], U2[5], U2[6], U2[7]);
      dst[6] = make_float4(U2[8], U2[9], U2[10], U2[11]);
      dst[7] = make_float4(U2[12], U2[13], U2[14], U2[15]);
      s_part[wv][ln][32] = RS;
    }
    __syncthreads();
    float fU1[16], fU2[16], fRS = 0.f;
    #pragma unroll
    for (int p = 0; p < 16; ++p) { fU1[p] = 0.f; fU2[p] = 0.f; }
    #pragma unroll
    for (int w2 = 0; w2 < NW; ++w2) {
      const float4* src = (const float4*)&s_part[w2][j][0];
      float4 q0 = src[0], q1 = src[1], q2 = src[2], q3 = src[3];
      float4 q4 = src[4], q5 = src[5], q6 = src[6], q7 = src[7];
      fU1[0] += q0.x; fU1[1] += q0.y; fU1[2] += q0.z; fU1[3] += q0.w;
      fU1[4] += q1.x; fU1[5] += q1.y; fU1[6] += q1.z; fU1[7] += q1.w;
      fU1[8] += q2.x; fU1[9] += q2.y; fU1[10] += q2.z; fU1[11] += q2.w;
      fU1[12] += q3.x; fU1[13] += q3.y; fU1[14] += q3.z; fU1[15] += q3.w;
      fU2[0] += q4.x; fU2[1] += q4.y; fU2[2] += q4.z; fU2[3] += q4.w;
      fU2[4] += q5.x; fU2[5] += q5.y; fU2[6] += q5.z; fU2[7] += q5.w;
      fU2[8] += q6.x; fU2[9] += q6.y; fU2[10] += q6.z; fU2[11] += q6.w;
      fU2[12] += q7.x; fU2[13] += q7.y; fU2[14] += q7.z; fU2[15] += q7.w;
      fRS += s_part[w2][j][32];
    }
    __syncthreads();   // protect s_part before next iteration's writes

    // ---- stats, fully in-lane ----
    const float inv = 1.f / (fRS + EM_EPS);
    const float Cc  = fRS * inv;
    float s2v[16];
    #pragma unroll
    for (int p = 0; p < 16; ++p) {
      mu[p] = fU1[p] * inv;
      float s2 = fU2[p] * inv - mu[p] * mu[p] * (2.f - Cc);
      s2 = fmaxf(s2, 0.f) + EM_EPS;
      s2v[p] = s2;
      i2s[p] = 0.5f * __builtin_amdgcn_rcpf(s2);
    }
    const float pr0 = (s2v[0] * s2v[1]) * (s2v[2] * s2v[3]);
    const float pr1 = (s2v[4] * s2v[5]) * (s2v[6] * s2v[7]);
    const float pr2 = (s2v[8] * s2v[9]) * (s2v[10] * s2v[11]);
    const float pr3 = (s2v[12] * s2v[13]) * (s2v[14] * s2v[15]);
    const float lsum = (__logf(pr0) + __logf(pr1)) + (__logf(pr2) + __logf(pr3));
    const float cost = (16.f * bu_j + 0.5f * lsum) * fRS;
    const float aout = 1.f / (1.f + __expf(-(lam * (ba_j - cost))));

    if (it < 2) {
      const float L0 = -0.5f * (16.f * LOG2PI + lsum);
      const float lj = L0 + __logf(aout + EM_EPS);
      float mj = jvalid ? lj : -1e30f;
      mj = fmaxf(mj, __shfl_xor(mj, 1));
      mj = fmaxf(mj, __shfl_xor(mj, 2));
      mj = fmaxf(mj, __shfl_xor(mj, 4));
      mj = fmaxf(mj, __shfl_xor(mj, 8));
      Ej = jvalid ? __expf(lj - mj) : 0.f;
    } else if (wv == 0 && ln < 16 && jvalid) {
      aout_g[((b * B + j) * OH + oy) * OW + ox] = aout;
      if (pose_out_g) {
        #pragma unroll
        for (int p = 0; p < 16; ++p)
          pose_out_g[((b * (B * 16) + j * 16 + p) * OH + oy) * OW + ox] = mu[p];
      }
    }
  }
}

// ---------------- spatial mean ----------------
__global__ __launch_bounds__(64) void k_mean(const float* __restrict__ a4,
                                             float* __restrict__ out) {
  int idx = blockIdx.x * 64 + threadIdx.x;
  if (idx >= 320) return;
  const float* pa = a4 + idx * 25;
  float s = 0.f;
  #pragma unroll
  for (int i = 0; i < 25; ++i) s += pa[i];
  out[idx] = s * (1.f / 25.f);
}

extern "C" void kernel_launch(void* const* d_in, const int* in_sizes, int n_in,
                              void* d_out, int out_size, void* d_ws, size_t ws_size,
                              hipStream_t stream) {
  const float* x       = (const float*)d_in[0];
  const float* conv1_w = (const float*)d_in[1];
  const float* bn1_g   = (const float*)d_in[2];
  const float* bn1_b   = (const float*)d_in[3];
  const float* conva_w = (const float*)d_in[4];
  const float* bna_g   = (const float*)d_in[5];
  const float* bna_b   = (const float*)d_in[6];
  const float* convp_w = (const float*)d_in[7];
  const float* bnp_g   = (const float*)d_in[8];
  const float* bnp_b   = (const float*)d_in[9];
  const float* W1      = (const float*)d_in[10];
  const float* bu1     = (const float*)d_in[11];
  const float* ba1     = (const float*)d_in[12];
  const float* bnc1_g  = (const float*)d_in[13];
  const float* bnc1_b  = (const float*)d_in[14];
  const float* W2      = (const float*)d_in[15];
  const float* bu2     = (const float*)d_in[16];
  const float* ba2     = (const float*)d_in[17];
  const float* bnc2_g  = (const float*)d_in[18];
  const float* bnc2_b  = (const float*)d_in[19];
  const float* Wfc     = (const float*)d_in[20];
  const float* bufc    = (const float*)d_in[21];
  const float* bafc    = (const float*)d_in[22];

  float* ws    = (float*)d_ws;
  float* out1  = ws;                          // 32*256*14*14 = 1605632
  float* a1    = out1  + 32 * 256 * 14 * 14;  // 73728
  float* pose1 = a1    + 32 * 16 * 12 * 12;   // 1179648
  float* a2    = pose1 + 32 * 256 * 12 * 12;  // 18432
  float* pose2 = a2    + 32 * 16 * 6 * 6;     // 294912
  float* a3    = pose2 + 32 * 256 * 6 * 6;    // 18432
  float* pose3 = a3    + 32 * 16 * 6 * 6;     // 294912
  float* a4    = pose3 + 32 * 256 * 6 * 6;    // 8000
  float* partial = a4  + 8000;                // 4*32*288*144 = 5308416
  const size_t base_floats = 3493696;
  const size_t need = (base_floats + (size_t)4 * 32 * 288 * 144) * 4;

  k_conv1<<<6272, 256, 0, stream>>>(x, conv1_w, bn1_g, bn1_b, out1);
  if (ws_size >= need) {
    k_conv2_part<<<1152, 192, 0, stream>>>(out1, conva_w, convp_w, partial);
    k_conv2_red<<<4896, 256, 0, stream>>>(partial, bna_g, bna_b, bnp_g, bnp_b,
                                          a1, pose1);
  } else {
    k_conv2<<<288, 192, 0, stream>>>(out1, conva_w, convp_w, bna_g, bna_b,
                                     bnp_g, bnp_b, a1, pose1);
  }
  k_routing<3, 2, 1, 12, 12, 6, 6, 16><<<32 * 36, 256, 0, stream>>>(
      a1, pose1, W1, bu1, ba1, nullptr, nullptr, a2, pose2);
  k_routing<3, 1, 1, 6, 6, 6, 6, 16><<<32 * 36, 256, 0, stream>>>(
      a2, pose2, W2, bu2, ba2, bnc1_g, bnc1_b, a3, pose3);
  k_routing<4, 1, 1, 6, 6, 5, 5, 10><<<32 * 25, 256, 0, stream>>>(
      a3, pose3, Wfc, bufc, bafc, bnc2_g, bnc2_b, a4, nullptr);
  k_mean<<<5, 64, 0, stream>>>(a4, (float*)d_out);
}

// Round 8
// 580.651 us; speedup vs baseline: 1.2120x; 1.2120x over previous
//
#include <hip/hip_runtime.h>
#include <math.h>

#define EM_EPS 1e-8f
#define BN_SC 0.999995000037f   // 1/sqrt(1+1e-5)
#define LOG2PI 1.8378770664093453f

// ---------------- conv1 (5x5 s2 VALID) + bn1 ----------------
// x (32,3,32,32), w (256,3,5,5) -> out (32,256,14,14)
__global__ __launch_bounds__(256) void k_conv1(
    const float* __restrict__ x, const float* __restrict__ w,
    const float* __restrict__ g, const float* __restrict__ bb,
    float* __restrict__ out) {
  int idx = blockIdx.x * 256 + threadIdx.x;
  int ox = idx % 14; int t = idx / 14;
  int oy = t % 14; t /= 14;
  int co = t % 256; int b = t / 256;
  const float* xb = x + b * 3 * 1024;
  const float* wc = w + co * 75;
  float acc = 0.f;
  #pragma unroll
  for (int ci = 0; ci < 3; ++ci) {
    const float* xc = xb + ci * 1024 + (oy * 2) * 32 + ox * 2;
    const float* wk = wc + ci * 25;
    #pragma unroll
    for (int kh = 0; kh < 5; ++kh)
      #pragma unroll
      for (int kw = 0; kw < 5; ++kw)
        acc = fmaf(xc[kh * 32 + kw], wk[kh * 5 + kw], acc);
  }
  out[idx] = acc * (g[co] * BN_SC) + bb[co];
}

// ------------- conv2 partial (K-split over 4 blocks) -------------
__global__ __launch_bounds__(192) void k_conv2_part(
    const float* __restrict__ in,
    const float* __restrict__ wa, const float* __restrict__ wp,
    float* __restrict__ partial) {
  __shared__ float s_in[16 * 14 * 16];   // [ci][iy][ix pad16]
  __shared__ float s_w[16 * 9 * 34];     // [ci][tap][co pad34]

  const int t   = threadIdx.x;
  const int row = t >> 4;
  const int cg  = t & 15;
  const int b   = blockIdx.x / 36;
  const int r36 = blockIdx.x % 36;
  const int gco = (r36 >> 2) * 32;
  const int kc  = r36 & 3;
  const float* inb = in + b * 50176;

  float acc[2][12];
  #pragma unroll
  for (int u = 0; u < 2; ++u)
    #pragma unroll
    for (int px = 0; px < 12; ++px) acc[u][px] = 0.f;

  for (int ch = kc * 4; ch < kc * 4 + 4; ++ch) {
    __syncthreads();
    for (int idx = t; idx < 3136; idx += 192) {
      int ci = idx / 196, r = idx - ci * 196;
      int iy = r / 14, ix = r - iy * 14;
      s_in[ci * 224 + iy * 16 + ix] = inb[ch * 3136 + idx];
    }
    for (int idx = t; idx < 4608; idx += 192) {
      int co = idx / 144, rem = idx - co * 144;
      int c = gco + co;
      float val = 0.f;
      if (c < 272) {
        const float* wrow = (c < 16) ? (wa + c * 2304) : (wp + (c - 16) * 2304);
        val = wrow[ch * 144 + rem];
      }
      s_w[rem * 34 + co] = val;
    }
    __syncthreads();

    for (int ci = 0; ci < 16; ++ci) {
      float rin[3][16];
      #pragma unroll
      for (int kh = 0; kh < 3; ++kh) {
        const float4* rp = (const float4*)&s_in[ci * 224 + (row + kh) * 16];
        #pragma unroll
        for (int x = 0; x < 4; ++x)
          *(float4*)&rin[kh][x * 4] = rp[x];
      }
      #pragma unroll
      for (int kh = 0; kh < 3; ++kh) {
        #pragma unroll
        for (int kw = 0; kw < 3; ++kw) {
          float2 wv = *(const float2*)&s_w[(ci * 9 + kh * 3 + kw) * 34 + cg * 2];
          #pragma unroll
          for (int px = 0; px < 12; ++px) {
            float iv = rin[kh][px + kw];
            acc[0][px] = fmaf(iv, wv.x, acc[0][px]);
            acc[1][px] = fmaf(iv, wv.y, acc[1][px]);
          }
        }
      }
    }
  }

  #pragma unroll
  for (int u = 0; u < 2; ++u) {
    int c = gco + cg * 2 + u;
    float* dst = partial + ((size_t)(kc * 32 + b) * 288 + c) * 144 + row * 12;
    #pragma unroll
    for (int px = 0; px < 12; ++px) dst[px] = acc[u][px];
  }
}

// ------------- conv2 reduce: sum 4 partials + bn (+sigmoid for a) -------------
__global__ __launch_bounds__(256) void k_conv2_red(
    const float* __restrict__ partial,
    const float* __restrict__ ga, const float* __restrict__ bba,
    const float* __restrict__ gp, const float* __restrict__ bbp,
    float* __restrict__ a1, float* __restrict__ pose1) {
  int idx = blockIdx.x * 256 + threadIdx.x;
  if (idx >= 32 * 272 * 144) return;
  int px = idx % 144; int r = idx / 144;
  int c = r % 272; int b = r / 272;
  const size_t base = ((size_t)b * 288 + c) * 144 + px;
  const size_t kstr = (size_t)32 * 288 * 144;
  float s = partial[base] + partial[base + kstr]
          + partial[base + 2 * kstr] + partial[base + 3 * kstr];
  if (c < 16) {
    float v = s * (ga[c] * BN_SC) + bba[c];
    a1[((size_t)b * 16 + c) * 144 + px] = 1.f / (1.f + expf(-v));
  } else {
    int cp = c - 16;
    pose1[((size_t)b * 256 + cp) * 144 + px] = s * (gp[cp] * BN_SC) + bbp[cp];
  }
}

// ------------- conv2 single-pass fallback (ws too small) -------------
__global__ __launch_bounds__(192) void k_conv2(
    const float* __restrict__ in,
    const float* __restrict__ wa, const float* __restrict__ wp,
    const float* __restrict__ ga, const float* __restrict__ bba,
    const float* __restrict__ gp, const float* __restrict__ bbp,
    float* __restrict__ a1, float* __restrict__ pose1) {
  __shared__ float s_in[16 * 14 * 16];
  __shared__ float s_w[16 * 9 * 34];

  const int t   = threadIdx.x;
  const int row = t >> 4;
  const int cg  = t & 15;
  const int b   = blockIdx.x / 9;
  const int gco = (blockIdx.x % 9) * 32;
  const float* inb = in + b * 50176;

  float acc[2][12];
  #pragma unroll
  for (int u = 0; u < 2; ++u)
    #pragma unroll
    for (int px = 0; px < 12; ++px) acc[u][px] = 0.f;

  for (int ch = 0; ch < 16; ++ch) {
    __syncthreads();
    for (int idx = t; idx < 3136; idx += 192) {
      int ci = idx / 196, r = idx - ci * 196;
      int iy = r / 14, ix = r - iy * 14;
      s_in[ci * 224 + iy * 16 + ix] = inb[ch * 3136 + idx];
    }
    for (int idx = t; idx < 4608; idx += 192) {
      int co = idx / 144, rem = idx - co * 144;
      int c = gco + co;
      float val = 0.f;
      if (c < 272) {
        const float* wrow = (c < 16) ? (wa + c * 2304) : (wp + (c - 16) * 2304);
        val = wrow[ch * 144 + rem];
      }
      s_w[rem * 34 + co] = val;
    }
    __syncthreads();

    for (int ci = 0; ci < 16; ++ci) {
      float rin[3][16];
      #pragma unroll
      for (int kh = 0; kh < 3; ++kh) {
        const float4* rp = (const float4*)&s_in[ci * 224 + (row + kh) * 16];
        #pragma unroll
        for (int x = 0; x < 4; ++x)
          *(float4*)&rin[kh][x * 4] = rp[x];
      }
      #pragma unroll
      for (int kh = 0; kh < 3; ++kh) {
        #pragma unroll
        for (int kw = 0; kw < 3; ++kw) {
          float2 wv = *(const float2*)&s_w[(ci * 9 + kh * 3 + kw) * 34 + cg * 2];
          #pragma unroll
          for (int px = 0; px < 12; ++px) {
            float iv = rin[kh][px + kw];
            acc[0][px] = fmaf(iv, wv.x, acc[0][px]);
            acc[1][px] = fmaf(iv, wv.y, acc[1][px]);
          }
        }
      }
    }
  }

  #pragma unroll
  for (int u = 0; u < 2; ++u) {
    int c = gco + cg * 2 + u;
    if (c >= 272) continue;
    if (c < 16) {
      float g_ = ga[c] * BN_SC, b_ = bba[c];
      float* dst = a1 + ((b * 16 + c) * 12 + row) * 12;
      #pragma unroll
      for (int px = 0; px < 12; ++px) {
        float v = acc[u][px] * g_ + b_;
        dst[px] = 1.f / (1.f + expf(-v));
      }
    } else {
      int cp = c - 16;
      float g_ = gp[cp] * BN_SC, b_ = bbp[cp];
      float* dst = pose1 + ((b * 256 + cp) * 12 + row) * 12;
      #pragma unroll
      for (int px = 0; px < 12; ++px)
        dst[px] = acc[u][px] * g_ + b_;
    }
  }
}

// ---------------- EM routing v4: lane = (kq, j), all 16 p in-lane ----------------
// 256 threads = 4 waves; wave wv owns k in [wv*KPW, (wv+1)*KPW); lane kq
// handles k = wv*KPW + st*4 + kq for capsule j. p-reductions in-lane (no
// shuffles); only the j-softmax shuffles (4 per quad-step). W read once per
// (k,j) -> 1x redundancy. launch_bounds(256,2): 256-VGPR budget, no spill.
template<int K, int S, int P, int HIN, int WIN, int OH, int OW, int B>
__global__ __launch_bounds__(256, 2) void k_routing(
    const float* __restrict__ ag,      // (b,16,HIN,WIN)
    const float* __restrict__ poseg,   // (b,256,HIN,WIN)
    const float* __restrict__ Wg,      // (KKA,B,4,4)
    const float* __restrict__ bu, const float* __restrict__ ba,
    const float* __restrict__ bng, const float* __restrict__ bnb,
    float* __restrict__ aout_g,        // (b,B,OH,OW)
    float* __restrict__ pose_out_g) {  // (b,B*16,OH,OW) or null
  constexpr int A = 16;
  constexpr int KK = K * K;
  constexpr int KKA = KK * A;
  constexpr int NW = 4;
  constexpr int KPW = KKA / NW;       // 36 or 64
  constexpr int NSTEP = KPW / 4;      // 9 or 16
  static_assert(KPW % 4 == 0, "KPW%4");

  __shared__ __attribute__((aligned(16))) float s_pp[KKA * 16];
  __shared__ float s_ain[KKA];
  __shared__ __attribute__((aligned(16))) float s_part[NW][16][36]; // U1[16]|U2[16]|RS pad36

  const int t  = threadIdx.x;
  const int wv = t >> 6;
  const int ln = t & 63;
  const int j  = ln & 15;
  const int kq = ln >> 4;
  const int jc = (j < B) ? j : 0;
  const bool jvalid = (j < B);

  const int bi = blockIdx.x;
  const int b  = bi / (OH * OW);
  const int l  = bi % (OH * OW);
  const int oy = l / OW, ox = l % OW;

  // ---- stage pose patch (+bn) and a patch into LDS ----
  for (int idx = t; idx < KKA * 16; idx += 256) {
    int k = idx >> 4, pe = idx & 15;
    int acap = k & 15, kki = k >> 4;
    int kh = kki / K, kw = kki % K;
    int iy = oy * S - P + kh, ix = ox * S - P + kw;
    float val = 0.f;
    if (iy >= 0 && iy < HIN && ix >= 0 && ix < WIN) {
      int c = acap * 16 + pe;
      val = poseg[((b * 256 + c) * HIN + iy) * WIN + ix];
      if (bng) val = val * (bng[c] * BN_SC) + bnb[c];
    }
    s_pp[idx] = val;
  }
  for (int k = t; k < KKA; k += 256) {
    int acap = k & 15, kki = k >> 4;
    int kh = kki / K, kw = kki % K;
    int iy = oy * S - P + kh, ix = ox * S - P + kw;
    float val = 0.f;
    if (iy >= 0 && iy < HIN && ix >= 0 && ix < WIN)
      val = ag[((b * A + acap) * HIN + iy) * WIN + ix];
    s_ain[k] = val;
  }
  __syncthreads();

  const float bu_j = bu[jc];
  const float ba_j = ba[jc];
  const int kbase = wv * KPW + kq;
  const float* wjc = Wg + (size_t)jc * 16;   // row base for this lane's j

  float mu[16], i2s[16];
  #pragma unroll
  for (int p = 0; p < 16; ++p) { mu[p] = 0.f; i2s[p] = 0.f; }
  float Ej = 0.f;

  float p95 = 0.95f;
  for (int it = 0; it < 3; ++it) {
    const float lam = 0.01f * (1.0f - p95);
    p95 *= 0.95f;
    float U1[16], U2[16], RS = 0.f;
    #pragma unroll
    for (int p = 0; p < 16; ++p) { U1[p] = 0.f; U2[p] = 0.f; }

    for (int st = 0; st < NSTEP; ++st) {
      const int k = kbase + st * 4;
      const float4* wrp = (const float4*)(wjc + (size_t)k * B * 16);
      const float4 cw0 = wrp[0], cw1 = wrp[1], cw2 = wrp[2], cw3 = wrp[3];
      const float4* pr = (const float4*)&s_pp[k * 16];
      const float ain = s_ain[k];
      float vv[16];
      #pragma unroll
      for (int x2 = 0; x2 < 4; ++x2) {
        const float4 p4 = pr[x2];
        vv[x2 * 4 + 0] = p4.x * cw0.x + p4.y * cw1.x + p4.z * cw2.x + p4.w * cw3.x;
        vv[x2 * 4 + 1] = p4.x * cw0.y + p4.y * cw1.y + p4.z * cw2.y + p4.w * cw3.y;
        vv[x2 * 4 + 2] = p4.x * cw0.z + p4.y * cw1.z + p4.z * cw2.z + p4.w * cw3.z;
        vv[x2 * 4 + 3] = p4.x * cw0.w + p4.y * cw1.w + p4.z * cw2.w + p4.w * cw3.w;
      }
      float ra;
      if (it == 0) {
        ra = ain * (1.0f / (float)B);
      } else {
        float sa = 0.f, sb = 0.f, sc = 0.f, sd = 0.f;
        #pragma unroll
        for (int g = 0; g < 4; ++g) {
          float d0 = vv[g * 4 + 0] - mu[g * 4 + 0];
          float d1 = vv[g * 4 + 1] - mu[g * 4 + 1];
          float d2 = vv[g * 4 + 2] - mu[g * 4 + 2];
          float d3 = vv[g * 4 + 3] - mu[g * 4 + 3];
          sa = fmaf(d0 * i2s[g * 4 + 0], d0, sa);
          sb = fmaf(d1 * i2s[g * 4 + 1], d1, sb);
          sc = fmaf(d2 * i2s[g * 4 + 2], d2, sc);
          sd = fmaf(d3 * i2s[g * 4 + 3], d3, sd);
        }
        const float ss = (sa + sb) + (sc + sd);
        float e = Ej * __expf(-ss);
        float sm = e + __shfl_xor(e, 1);
        sm += __shfl_xor(sm, 2);
        sm += __shfl_xor(sm, 4);
        sm += __shfl_xor(sm, 8);
        ra = e * __builtin_amdgcn_rcpf(sm + 1e-30f) * ain;
      }
      RS += ra;
      #pragma unroll
      for (int p = 0; p < 16; ++p) {
        float tv = ra * vv[p];
        U1[p] += tv;
        U2[p] = fmaf(tv, vv[p], U2[p]);
      }
    }

    // ---- reduce over kq (in-wave butterfly) ----
    #pragma unroll
    for (int p = 0; p < 16; ++p) {
      U1[p] += __shfl_xor(U1[p], 16); U1[p] += __shfl_xor(U1[p], 32);
      U2[p] += __shfl_xor(U2[p], 16); U2[p] += __shfl_xor(U2[p], 32);
    }
    RS += __shfl_xor(RS, 16); RS += __shfl_xor(RS, 32);

    // ---- cross-wave exchange ----
    if (ln < 16) {
      float4* dst = (float4*)&s_part[wv][ln][0];
      dst[0] = make_float4(U1[0], U1[1], U1[2], U1[3]);
      dst[1] = make_float4(U1[4], U1[5], U1[6], U1[7]);
      dst[2] = make_float4(U1[8], U1[9], U1[10], U1[11]);
      dst[3] = make_float4(U1[12], U1[13], U1[14], U1[15]);
      dst[4] = make_float4(U2[0], U2[1], U2[2], U2[3]);
      dst[5] = make_float4(U2[4], U2[5], U2[6], U2[7]);
      dst[6] = make_float4(U2[8], U2[9], U2[10], U2[11]);
      dst[7] = make_float4(U2[12], U2[13], U2[14], U2[15]);
      s_part[wv][ln][32] = RS;
    }
    __syncthreads();
    float fU1[16], fU2[16], fRS = 0.f;
    #pragma unroll
    for (int p = 0; p < 16; ++p) { fU1[p] = 0.f; fU2[p] = 0.f; }
    #pragma unroll
    for (int w2 = 0; w2 < NW; ++w2) {
      const float4* src = (const float4*)&s_part[w2][j][0];
      float4 q0 = src[0], q1 = src[1], q2 = src[2], q3 = src[3];
      float4 q4 = src[4], q5 = src[5], q6 = src[6], q7 = src[7];
      fU1[0] += q0.x; fU1[1] += q0.y; fU1[2] += q0.z; fU1[3] += q0.w;
      fU1[4] += q1.x; fU1[5] += q1.y; fU1[6] += q1.z; fU1[7] += q1.w;
      fU1[8] += q2.x; fU1[9] += q2.y; fU1[10] += q2.z; fU1[11] += q2.w;
      fU1[12] += q3.x; fU1[13] += q3.y; fU1[14] += q3.z; fU1[15] += q3.w;
      fU2[0] += q4.x; fU2[1] += q4.y; fU2[2] += q4.z; fU2[3] += q4.w;
      fU2[4] += q5.x; fU2[5] += q5.y; fU2[6] += q5.z; fU2[7] += q5.w;
      fU2[8] += q6.x; fU2[9] += q6.y; fU2[10] += q6.z; fU2[11] += q6.w;
      fU2[12] += q7.x; fU2[13] += q7.y; fU2[14] += q7.z; fU2[15] += q7.w;
      fRS += s_part[w2][j][32];
    }
    __syncthreads();   // protect s_part before next iteration's writes

    // ---- stats, fully in-lane ----
    const float inv = 1.f / (fRS + EM_EPS);
    const float Cc  = fRS * inv;
    float s2v[16];
    #pragma unroll
    for (int p = 0; p < 16; ++p) {
      mu[p] = fU1[p] * inv;
      float s2 = fU2[p] * inv - mu[p] * mu[p] * (2.f - Cc);
      s2 = fmaxf(s2, 0.f) + EM_EPS;
      s2v[p] = s2;
      i2s[p] = 0.5f * __builtin_amdgcn_rcpf(s2);
    }
    const float pr0 = (s2v[0] * s2v[1]) * (s2v[2] * s2v[3]);
    const float pr1 = (s2v[4] * s2v[5]) * (s2v[6] * s2v[7]);
    const float pr2 = (s2v[8] * s2v[9]) * (s2v[10] * s2v[11]);
    const float pr3 = (s2v[12] * s2v[13]) * (s2v[14] * s2v[15]);
    const float lsum = (__logf(pr0) + __logf(pr1)) + (__logf(pr2) + __logf(pr3));
    const float cost = (16.f * bu_j + 0.5f * lsum) * fRS;
    const float aout = 1.f / (1.f + __expf(-(lam * (ba_j - cost))));

    if (it < 2) {
      const float L0 = -0.5f * (16.f * LOG2PI + lsum);
      const float lj = L0 + __logf(aout + EM_EPS);
      float mj = jvalid ? lj : -1e30f;
      mj = fmaxf(mj, __shfl_xor(mj, 1));
      mj = fmaxf(mj, __shfl_xor(mj, 2));
      mj = fmaxf(mj, __shfl_xor(mj, 4));
      mj = fmaxf(mj, __shfl_xor(mj, 8));
      Ej = jvalid ? __expf(lj - mj) : 0.f;
    } else if (wv == 0 && ln < 16 && jvalid) {
      aout_g[((b * B + j) * OH + oy) * OW + ox] = aout;
      if (pose_out_g) {
        #pragma unroll
        for (int p = 0; p < 16; ++p)
          pose_out_g[((b * (B * 16) + j * 16 + p) * OH + oy) * OW + ox] = mu[p];
      }
    }
  }
}

// ---------------- spatial mean ----------------
__global__ __launch_bounds__(64) void k_mean(const float* __restrict__ a4,
                                             float* __restrict__ out) {
  int idx = blockIdx.x * 64 + threadIdx.x;
  if (idx >= 320) return;
  const float* pa = a4 + idx * 25;
  float s = 0.f;
  #pragma unroll
  for (int i = 0; i < 25; ++i) s += pa[i];
  out[idx] = s * (1.f / 25.f);
}

extern "C" void kernel_launch(void* const* d_in, const int* in_sizes, int n_in,
                              void* d_out, int out_size, void* d_ws, size_t ws_size,
                              hipStream_t stream) {
  const float* x       = (const float*)d_in[0];
  const float* conv1_w = (const float*)d_in[1];
  const float* bn1_g   = (const float*)d_in[2];
  const float* bn1_b   = (const float*)d_in[3];
  const float* conva_w = (const float*)d_in[4];
  const float* bna_g   = (const float*)d_in[5];
  const float* bna_b   = (const float*)d_in[6];
  const float* convp_w = (const float*)d_in[7];
  const float* bnp_g   = (const float*)d_in[8];
  const float* bnp_b   = (const float*)d_in[9];
  const float* W1      = (const float*)d_in[10];
  const float* bu1     = (const float*)d_in[11];
  const float* ba1     = (const float*)d_in[12];
  const float* bnc1_g  = (const float*)d_in[13];
  const float* bnc1_b  = (const float*)d_in[14];
  const float* W2      = (const float*)d_in[15];
  const float* bu2     = (const float*)d_in[16];
  const float* ba2     = (const float*)d_in[17];
  const float* bnc2_g  = (const float*)d_in[18];
  const float* bnc2_b  = (const float*)d_in[19];
  const float* Wfc     = (const float*)d_in[20];
  const float* bufc    = (const float*)d_in[21];
  const float* bafc    = (const float*)d_in[22];

  float* ws    = (float*)d_ws;
  float* out1  = ws;                          // 32*256*14*14 = 1605632
  float* a1    = out1  + 32 * 256 * 14 * 14;  // 73728
  float* pose1 = a1    + 32 * 16 * 12 * 12;   // 1179648
  float* a2    = pose1 + 32 * 256 * 12 * 12;  // 18432
  float* pose2 = a2    + 32 * 16 * 6 * 6;     // 294912
  float* a3    = pose2 + 32 * 256 * 6 * 6;    // 18432
  float* pose3 = a3    + 32 * 16 * 6 * 6;     // 294912
  float* a4    = pose3 + 32 * 256 * 6 * 6;    // 8000
  float* partial = a4  + 8000;                // 4*32*288*144 = 5308416
  const size_t base_floats = 3493696;
  const size_t need = (base_floats + (size_t)4 * 32 * 288 * 144) * 4;

  k_conv1<<<6272, 256, 0, stream>>>(x, conv1_w, bn1_g, bn1_b, out1);
  if (ws_size >= need) {
    k_conv2_part<<<1152, 192, 0, stream>>>(out1, conva_w, convp_w, partial);
    k_conv2_red<<<4896, 256, 0, stream>>>(partial, bna_g, bna_b, bnp_g, bnp_b,
                                          a1, pose1);
  } else {
    k_conv2<<<288, 192, 0, stream>>>(out1, conva_w, convp_w, bna_g, bna_b,
                                     bnp_g, bnp_b, a1, pose1);
  }
  k_routing<3, 2, 1, 12, 12, 6, 6, 16><<<32 * 36, 256, 0, stream>>>(
      a1, pose1, W1, bu1, ba1, nullptr, nullptr, a2, pose2);
  k_routing<3, 1, 1, 6, 6, 6, 6, 16><<<32 * 36, 256, 0, stream>>>(
      a2, pose2, W2, bu2, ba2, bnc1_g, bnc1_b, a3, pose3);
  k_routing<4, 1, 1, 6, 6, 5, 5, 10><<<32 * 25, 256, 0, stream>>>(
      a3, pose3, Wfc, bufc, bafc, bnc2_g, bnc2_b, a4, nullptr);
  k_mean<<<5, 64, 0, stream>>>(a4, (float*)d_out);
}